// Round 3
// baseline (510.468 us; speedup 1.0000x reference)
//
#include <hip/hip_runtime.h>

// Cost volume: out[n,c,d,h,w] = left[n,c,h,w] * right[n,c,h,w-d] (w>=d else 0)
// N=2 C=32 H=136 W=240 D=48. Output 401 MB fp32 -> write-BW bound.
//
// Round-5: change the WRITE-ADDRESS PATTERN, not the inner loop.
// Rounds 3-4 proved the limiter is insensitive to LDS conflicts, divisions,
// and NT-vs-plain stores: with grid=(H,NC) each block scatters 48x 960B
// chunks at 130,560B stride -> device-wide near-random ~1KB HBM bursts ->
// DRAM row-buffer thrash (~2.6 TB/s). fillBufferAligned hits 6.2 TB/s on the
// SAME buffer with one difference: contiguous streaming per workgroup.
// So: grid=(D,NC), one block per (nc,d) OUTPUT PLANE = 130,560 contiguous
// bytes streamed sequentially. Inputs (16.7 MB total) are LLC-resident; the
// 48x redundant left/right reads are cache hits and never touch HBM BW.
// No LDS, no barrier. Boundary w<d via clamped address + select (no
// divergent predicated loads).

constexpr int W   = 240;
constexpr int H   = 136;
constexpr int D   = 48;
constexpr int W4  = W / 4;              // 60 float4 per row
constexpr int HW4 = H * W4;             // 8160 float4 per output plane

typedef float v4f __attribute__((ext_vector_type(4)));

__global__ __launch_bounds__(256) void cost_volume_kernel(
    const float* __restrict__ left,
    const float* __restrict__ right,
    float* __restrict__ out)
{
    const int d  = blockIdx.x;          // 0..D-1
    const int nc = blockIdx.y;          // 0..NC-1

    const float* __restrict__ L = left  + (size_t)nc * (H * W);
    const float* __restrict__ R = right + (size_t)nc * (H * W);
    v4f* __restrict__ O = reinterpret_cast<v4f*>(out) + ((size_t)nc * D + d) * (size_t)HW4;

    // 256 threads stream one contiguous 127.5 KB plane: thread t writes
    // float4 i = t, t+256, ... -> every wave-store is 1 KB dense, and the
    // block's stores sweep the plane front-to-back (fill-kernel pattern).
    for (int i = threadIdx.x; i < HW4; i += 256) {
        const int h   = (unsigned)i / W4;      // magic-mul div
        const int w4  = i - h * W4;
        const int row = h * W;

        const v4f l = *reinterpret_cast<const v4f*>(L + row + 4 * w4);

        const int off = 4 * w4 - d;            // element offset into right row
        // clamped addresses are always in-bounds; select zeros where w<d
        const float r0 = R[row + ((off + 0 >= 0) ? off + 0 : 0)];
        const float r1 = R[row + ((off + 1 >= 0) ? off + 1 : 0)];
        const float r2 = R[row + ((off + 2 >= 0) ? off + 2 : 0)];
        const float r3 = R[row + ((off + 3 >= 0) ? off + 3 : 0)];

        v4f v;
        v.x = (off + 0 >= 0) ? l.x * r0 : 0.f;
        v.y = (off + 1 >= 0) ? l.y * r1 : 0.f;
        v.z = (off + 2 >= 0) ? l.z * r2 : 0.f;
        v.w = (off + 3 >= 0) ? l.w * r3 : 0.f;
        O[i] = v;
    }
}

extern "C" void kernel_launch(void* const* d_in, const int* in_sizes, int n_in,
                              void* d_out, int out_size, void* d_ws, size_t ws_size,
                              hipStream_t stream) {
    const float* left  = (const float*)d_in[0];
    const float* right = (const float*)d_in[1];
    float* out = (float*)d_out;
    const int rows = in_sizes[0] / W;   // N*C*H = 8704
    const int nc   = rows / H;          // N*C = 64
    dim3 grid(D, nc);
    cost_volume_kernel<<<grid, 256, 0, stream>>>(left, right, out);
}

// Round 4
// 409.936 us; speedup vs baseline: 1.2452x; 1.2452x over previous
//
#include <hip/hip_runtime.h>

// Cost volume: out[n,c,d,h,w] = left[n,c,h,w] * right[n,c,h,w-d] (w>=d else 0)
// N=2 C=32 H=136 W=240 D=48. Output 401 MB fp32 -> write-BW bound.
//
// Round-6: union of all lessons.
//  - R2-R4 (block=(h,nc), LDS, any inner loop): ~155-163us = 2.6 TB/s write.
//    960B write granules scattered at 127.5KiB stride -> HBM row-buffer
//    thrash; tRC-bound ceiling ~2.7 TB/s matches measurement.
//  - R5 (block=(d,nc), linear writes, per-lane cache gathers): 252us.
//    Writes fixed but reads blew up to ~800MB -> confounded regression.
// This version: block = (nc, 4-row h-tile) covering ALL 48 d.
//  - reads: each input row staged ONCE per block -> 16.7MB total (minimal)
//  - writes: per d, 240 threads write 4 rows = 3,840B CONTIGUOUS (4x granule)
//  - LDS: 4 shifted padded copies of each right row -> aligned conflict-free
//    ds_read_b128 for every d; left float4 hoisted to register before d-loop.
//    Steady state per output float4: 1 ds_read_b128 + 1 global_store_dwordx4.
//  - 22.3KB LDS -> 7 blocks/CU, 28 waves/CU; grid 34x64 = 2176 blocks.

constexpr int W    = 240;
constexpr int H    = 136;
constexpr int D    = 48;
constexpr int W4   = W / 4;          // 60 float4 per row
constexpr int ROWS = 4;              // h-rows per block
constexpr int NT   = H / ROWS;       // 34 h-tiles
constexpr int PAD  = D;              // 48 zero floats of left padding
constexpr int CLEN = PAD + W;        // 288 floats per shifted copy
constexpr int RTOT = 4 * ROWS * CLEN; // 4608 staged right floats

typedef float v4f __attribute__((ext_vector_type(4)));

__global__ __launch_bounds__(256) void cost_volume_kernel(
    const float* __restrict__ left,
    const float* __restrict__ right,
    float* __restrict__ out)
{
    // sR[j][r][x] = R[h0+r][x-48-j], 0 if OOB  (copy j = shift by j floats)
    __shared__ __align__(16) float sL[ROWS * W];
    __shared__ __align__(16) float sR[4][ROWS][CLEN];

    const int ht  = blockIdx.x;      // 0..NT-1
    const int nc  = blockIdx.y;      // 0..NC-1
    const int h0  = ht * ROWS;
    const int tid = threadIdx.x;

    const float* __restrict__ Lg = left  + (size_t)(nc * H + h0) * W;
    const float* __restrict__ Rg = right + (size_t)(nc * H + h0) * W;

    // Stage left: 4 contiguous rows = 240 float4, fully coalesced.
    if (tid < ROWS * W4) {
        reinterpret_cast<v4f*>(sL)[tid] =
            reinterpret_cast<const v4f*>(Lg)[tid];
    }
    // Stage right: 4608 scalar writes (18 per thread), coalesced-ish reads.
    for (int y = tid; y < RTOT; y += 256) {
        const int j   = y / (ROWS * CLEN);
        const int rem = y - j * (ROWS * CLEN);
        const int r   = rem / CLEN;
        const int x   = rem - r * CLEN;
        const int src = x - PAD - j;           // always < W
        sR[0][0][y] = (src >= 0) ? Rg[r * W + src] : 0.0f;
    }
    __syncthreads();

    if (tid >= ROWS * W4) return;    // 240 active threads

    const int r  = tid / W4;         // row within tile (constant per thread)
    const int w4 = tid - r * W4;     // float4 column    (constant per thread)

    const v4f l4 = reinterpret_cast<const v4f*>(sL)[tid];  // hoisted left

    // Output base for d=0 at this (row, w4); each d adds H*W4 float4.
    v4f* __restrict__ o = reinterpret_cast<v4f*>(out)
        + ((size_t)nc * D * H + (h0 + r)) * (size_t)W4 + w4;
    const size_t ds4 = (size_t)H * W4;

    const v4f* C0 = reinterpret_cast<const v4f*>(sR[0][r]);
    const v4f* C1 = reinterpret_cast<const v4f*>(sR[1][r]);
    const v4f* C2 = reinterpret_cast<const v4f*>(sR[2][r]);
    const v4f* C3 = reinterpret_cast<const v4f*>(sR[3][r]);

    // d = 4q + j ; copy j at float4 index (w4 + 12 - q) gives R[w+k-d].
    #pragma unroll
    for (int q = 0; q < D / 4; ++q) {
        const int base = w4 + PAD / 4 - q;     // 1..71, aligned b128
        const v4f r0 = C0[base];
        const v4f r1 = C1[base];
        const v4f r2 = C2[base];
        const v4f r3 = C3[base];
        v4f* oq = o + (size_t)(4 * q) * ds4;
        oq[0]       = l4 * r0;
        oq[ds4]     = l4 * r1;
        oq[2 * ds4] = l4 * r2;
        oq[3 * ds4] = l4 * r3;
    }
}

extern "C" void kernel_launch(void* const* d_in, const int* in_sizes, int n_in,
                              void* d_out, int out_size, void* d_ws, size_t ws_size,
                              hipStream_t stream) {
    const float* left  = (const float*)d_in[0];
    const float* right = (const float*)d_in[1];
    float* out = (float*)d_out;
    const int rows = in_sizes[0] / W;   // N*C*H = 8704
    const int nc   = rows / H;          // N*C = 64
    dim3 grid(NT, nc);
    cost_volume_kernel<<<grid, 256, 0, stream>>>(left, right, out);
}